// Round 8
// baseline (2160.137 us; speedup 1.0000x reference)
//
#include <hip/hip_runtime.h>
#include <hip/hip_bf16.h>

// GNODE fully fused: y' = relu(y@W1+b1)@W2+b2, RK4(3/8) x10 steps (h=0.1),
// out = y@Wl+bl.  N=200000 rows, 128 ch, 64 out ch.
//
// Round 8 (from r7 counters: MfmaUtil 33, VALUBusy 38, occupancy LDS-capped):
// - 1024-thread blocks (16 waves share the one 65KB weight-LDS copy):
//   2 blocks/CU -> up to 32 waves/CU (was 8).  Matrix pipe oversubscribed
//   ~2.6x by 33%-duty waves -> MfmaUtil should approach saturation.
// - branch-free RNE bf16 conversion (4 VALU/elem, no NaN cndmask chain of
//   __float2bfloat16): cuts the dominant VALU cost (~340 -> ~130 ops/feval).
//   Same rounding as r2's passing run (finite data).
// - keep r7's 1-group-deep wA/wB weight prefetch + sched_barrier(0x6) fences
//   (bounded hoisting, no spill: FETCH/WRITE stayed at in+out).
//
// State recurrences (template<MODE>):
//   M1: U<-k1   M2: V<-k2   M3: U<-U+3(V+k3), V<-U-V+k3   M4: y+=h/8(U+k4)
// Layout identity (mfma_f32_16x16x32_bf16, HW-verified m89):
//   D:      ch = 16*mb + 4*(lane>>4) + r,               batch = lane&15
//   B-frag: ch = 32*kb + 16*(j>>2) + 4*(lane>>4)+(j&3),  batch = lane&15
// => frag[e>>3][e&7] = state[e], e = 4*mb + r.  All lane-local.

typedef __attribute__((ext_vector_type(8))) short bf16x8;
typedef __attribute__((ext_vector_type(4))) float f32x4;

constexpr float HS = 0.1f;

__device__ __forceinline__ short bf16s(float f) {
    unsigned u = __builtin_bit_cast(unsigned, f);
    u += 0x7fffu + ((u >> 16) & 1u);          // RNE (finite data, no NaN)
    return (short)(u >> 16);
}

#define MFMA_BF16 __builtin_amdgcn_mfma_f32_16x16x32_bf16
#define SBAR() __builtin_amdgcn_sched_barrier(0x6)

template<int M>
__device__ __forceinline__ bf16x8 build_frag(const float (&y)[32], const float (&U)[32],
                                             const float (&V)[32], int kb) {
    bf16x8 f;
    #pragma unroll
    for (int j = 0; j < 8; ++j) {
        const int e = kb * 8 + j;
        float a;
        if (M == 1)      a = y[e];
        else if (M == 2) a = fmaf(HS * (1.f / 3.f), U[e], y[e]);
        else if (M == 3) a = fmaf(-HS * (1.f / 3.f), U[e], fmaf(HS, V[e], y[e]));
        else             a = fmaf(HS, V[e], y[e]);
        f[j] = bf16s(a);
    }
    return f;
}

// One f-eval, 8 MFMA groups, 1-group-deep weight prefetch (wA/wB ping-pong).
template<int M>
__device__ __forceinline__ void feval(const uint4* __restrict__ sw1,
                                      const uint4* __restrict__ sw2,
                                      const float* __restrict__ sbf, int lane, int g,
                                      float (&y)[32], float (&U)[32], float (&V)[32])
{
    uint4 wA[8], wB[8];

    // acc = b1 (broadcast f32x4 reads, no VALU)
    f32x4 acc[8];
    #pragma unroll
    for (int mb = 0; mb < 8; ++mb)
        acc[mb] = *(const f32x4*)&sbf[mb * 16 + g * 4];
    // prefetch W1 group 0
    #pragma unroll
    for (int mb = 0; mb < 8; ++mb) wA[mb] = sw1[(mb * 4 + 0) * 64 + lane];

    // ---- matmul1 groups 0..3 ----
    bf16x8 f0 = build_frag<M>(y, U, V, 0);
    #pragma unroll
    for (int mb = 0; mb < 8; ++mb) wB[mb] = sw1[(mb * 4 + 1) * 64 + lane];
    #pragma unroll
    for (int mb = 0; mb < 8; ++mb)
        acc[mb] = MFMA_BF16(__builtin_bit_cast(bf16x8, wA[mb]), f0, acc[mb], 0, 0, 0);
    SBAR();

    bf16x8 f1 = build_frag<M>(y, U, V, 1);
    #pragma unroll
    for (int mb = 0; mb < 8; ++mb) wA[mb] = sw1[(mb * 4 + 2) * 64 + lane];
    #pragma unroll
    for (int mb = 0; mb < 8; ++mb)
        acc[mb] = MFMA_BF16(__builtin_bit_cast(bf16x8, wB[mb]), f1, acc[mb], 0, 0, 0);
    SBAR();

    bf16x8 f2 = build_frag<M>(y, U, V, 2);
    #pragma unroll
    for (int mb = 0; mb < 8; ++mb) wB[mb] = sw1[(mb * 4 + 3) * 64 + lane];
    #pragma unroll
    for (int mb = 0; mb < 8; ++mb)
        acc[mb] = MFMA_BF16(__builtin_bit_cast(bf16x8, wA[mb]), f2, acc[mb], 0, 0, 0);
    SBAR();

    bf16x8 f3 = build_frag<M>(y, U, V, 3);
    #pragma unroll
    for (int mb = 0; mb < 8; ++mb) wA[mb] = sw2[(mb * 4 + 0) * 64 + lane];   // W2 grp0
    #pragma unroll
    for (int mb = 0; mb < 8; ++mb)
        acc[mb] = MFMA_BF16(__builtin_bit_cast(bf16x8, wB[mb]), f3, acc[mb], 0, 0, 0);
    SBAR();

    // ---- relu -> h frags; acc2 = b2 ----
    bf16x8 h[4];
    #pragma unroll
    for (int mb = 0; mb < 8; ++mb)
        #pragma unroll
        for (int r = 0; r < 4; ++r)
            h[mb >> 1][(mb & 1) * 4 + r] = bf16s(fmaxf(acc[mb][r], 0.f));
    f32x4 acc2[8];
    #pragma unroll
    for (int mb = 0; mb < 8; ++mb)
        acc2[mb] = *(const f32x4*)&sbf[128 + mb * 16 + g * 4];

    // ---- matmul2 groups 4..7 ----
    #pragma unroll
    for (int mb = 0; mb < 8; ++mb) wB[mb] = sw2[(mb * 4 + 1) * 64 + lane];
    #pragma unroll
    for (int mb = 0; mb < 8; ++mb)
        acc2[mb] = MFMA_BF16(__builtin_bit_cast(bf16x8, wA[mb]), h[0], acc2[mb], 0, 0, 0);
    SBAR();

    #pragma unroll
    for (int mb = 0; mb < 8; ++mb) wA[mb] = sw2[(mb * 4 + 2) * 64 + lane];
    #pragma unroll
    for (int mb = 0; mb < 8; ++mb)
        acc2[mb] = MFMA_BF16(__builtin_bit_cast(bf16x8, wB[mb]), h[1], acc2[mb], 0, 0, 0);
    SBAR();

    #pragma unroll
    for (int mb = 0; mb < 8; ++mb) wB[mb] = sw2[(mb * 4 + 3) * 64 + lane];
    #pragma unroll
    for (int mb = 0; mb < 8; ++mb)
        acc2[mb] = MFMA_BF16(__builtin_bit_cast(bf16x8, wA[mb]), h[2], acc2[mb], 0, 0, 0);
    SBAR();

    #pragma unroll
    for (int mb = 0; mb < 8; ++mb)
        acc2[mb] = MFMA_BF16(__builtin_bit_cast(bf16x8, wB[mb]), h[3], acc2[mb], 0, 0, 0);
    SBAR();

    // ---- mode-fused writeback (no trailing fence: next feval's loads may hoist)
    #pragma unroll
    for (int mb = 0; mb < 8; ++mb)
        #pragma unroll
        for (int r = 0; r < 4; ++r) {
            const int e = mb * 4 + r;
            const float k = acc2[mb][r];
            if (M == 1)      U[e] = k;
            else if (M == 2) V[e] = k;
            else if (M == 3) {
                const float u = U[e], v = V[e];
                U[e] = fmaf(3.f, v + k, u);
                V[e] = u - v + k;
            } else {
                y[e] = fmaf(HS * 0.125f, U[e] + k, y[e]);
            }
        }
}

__global__ __launch_bounds__(1024) void gnode_kernel(
    const float* __restrict__ x, const uint4* __restrict__ wfr,
    const float* __restrict__ b1, const float* __restrict__ b2,
    const float* __restrict__ bl, float* __restrict__ out, int n)
{
    __shared__ uint4 s_w[4096];      // 64KB: W1 frags [0..2047], W2 [2048..4095]
    __shared__ float s_bf[256];      // 1KB: b1 [0..127], b2 [128..255]

    const int tid  = threadIdx.x;
    const int lane = tid & 63;
    const int wid  = tid >> 6;       // 0..15
    const int g    = lane >> 4;
    const int c16  = lane & 15;
    const int row  = blockIdx.x * 256 + wid * 16 + c16;  // this lane's batch row
    const int rowc = row < n ? row : n - 1;

    // ---- stage weights + biases into LDS (one-time, 16 waves share it)
    #pragma unroll
    for (int i = 0; i < 4; ++i) s_w[i * 1024 + tid] = wfr[i * 1024 + tid];
    if (tid < 256) s_bf[tid] = (tid < 128) ? b1[tid] : b2[tid - 128];

    // Y^T state, fp32 master: elem e=4*mb+r <-> (ch = 16*mb+4*g+r, batch=row)
    float y[32];
    {
        const f32x4* x4 = (const f32x4*)x;
        #pragma unroll
        for (int cb = 0; cb < 8; ++cb) {
            f32x4 v = x4[(size_t)rowc * 32 + cb * 4 + g];
            y[cb * 4 + 0] = v[0]; y[cb * 4 + 1] = v[1];
            y[cb * 4 + 2] = v[2]; y[cb * 4 + 3] = v[3];
        }
    }
    __syncthreads();

    const uint4* sw1 = s_w;
    const uint4* sw2 = s_w + 2048;

    float U[32], V[32];

    #pragma unroll 1
    for (int st = 0; st < 10; ++st) {
        feval<1>(sw1, sw2, s_bf, lane, g, y, U, V);   // U <- k1
        feval<2>(sw1, sw2, s_bf, lane, g, y, U, V);   // V <- k2
        feval<3>(sw1, sw2, s_bf, lane, g, y, U, V);   // fold k3
        feval<4>(sw1, sw2, s_bf, lane, g, y, U, V);   // y += h/8 (U + k4)
    }

    // ---- epilogue: out^T = Wl^T y^T + bl  (Wl frags straight from global)
    bf16x8 yf[4];
    #pragma unroll
    for (int e = 0; e < 32; ++e) yf[e >> 3][e & 7] = bf16s(y[e]);
    f32x4 ao[4];
    {
        const f32x4* bl4 = (const f32x4*)bl;
        #pragma unroll
        for (int mb = 0; mb < 4; ++mb) ao[mb] = bl4[mb * 4 + g];   // bl[16mb+4g+r]
    }
    #pragma unroll
    for (int f = 0; f < 16; ++f) {
        bf16x8 w = __builtin_bit_cast(bf16x8, wfr[(64 + f) * 64 + lane]);
        ao[f >> 2] = MFMA_BF16(w, yf[f & 3], ao[f >> 2], 0, 0, 0);
    }
    if (row < n) {
        f32x4* out4 = (f32x4*)out;
        #pragma unroll
        for (int mb = 0; mb < 4; ++mb)
            out4[(size_t)row * 16 + mb * 4 + g] = ao[mb];          // out[row][16mb+4g+r]
    }
}

// ---- prep: A-frag-linear bf16 weights into d_ws ----
// A-frag (16x32): lane l, elem j:  row = l&15 (+16*mb),
//                                  k   = 32*kb + 16*(j>>2) + 4*(l>>4) + (j&3)
// wfr[f*64+lane] : f 0..31 = W1 (mb=f>>2,kb=f&3), 32..63 = W2, 64..79 = Wl.
__global__ void prep_kernel(const float* __restrict__ W1, const float* __restrict__ W2,
                            const float* __restrict__ Wl, uint4* __restrict__ wfr)
{
    int t = blockIdx.x * 256 + threadIdx.x;
    if (t >= 80 * 64) return;
    int f = t >> 6, lane = t & 63;
    int gq = lane >> 4, c = lane & 15;
    const float* W; int mb, kv, cols;
    if (f < 32)      { W = W1; mb = f >> 2;        kv = f & 3;        cols = 128; }
    else if (f < 64) { W = W2; mb = (f - 32) >> 2; kv = (f - 32) & 3; cols = 128; }
    else             { W = Wl; mb = (f - 64) >> 2; kv = (f - 64) & 3; cols = 64;  }
    int col = mb * 16 + c;               // output-channel (A row)
    unsigned short v[8];
    #pragma unroll
    for (int j = 0; j < 8; ++j) {
        int k = kv * 32 + (j >> 2) * 16 + gq * 4 + (j & 3);
        unsigned u = __builtin_bit_cast(unsigned, W[k * cols + col]);
        u += 0x7fffu + ((u >> 16) & 1u);
        v[j] = (unsigned short)(u >> 16);
    }
    uint4 o;
    o.x = (unsigned)v[0] | ((unsigned)v[1] << 16);
    o.y = (unsigned)v[2] | ((unsigned)v[3] << 16);
    o.z = (unsigned)v[4] | ((unsigned)v[5] << 16);
    o.w = (unsigned)v[6] | ((unsigned)v[7] << 16);
    wfr[t] = o;
}

extern "C" void kernel_launch(void* const* d_in, const int* in_sizes, int n_in,
                              void* d_out, int out_size, void* d_ws, size_t ws_size,
                              hipStream_t stream)
{
    const float* x  = (const float*)d_in[0];
    const float* W1 = (const float*)d_in[1];
    const float* b1 = (const float*)d_in[2];
    const float* W2 = (const float*)d_in[3];
    const float* b2 = (const float*)d_in[4];
    const float* Wl = (const float*)d_in[5];
    const float* bl = (const float*)d_in[6];

    const int n = in_sizes[0] / 128;

    uint4* wfr = (uint4*)d_ws;                       // 80*64*16 = 81920 B

    prep_kernel<<<20, 256, 0, stream>>>(W1, W2, Wl, wfr);

    const int nb = (n + 255) / 256;          // 256 rows per block (16 waves x 16)
    gnode_kernel<<<nb, 1024, 0, stream>>>(x, wfr, b1, b2, bl, (float*)d_out, n);
}

// Round 9
// 792.186 us; speedup vs baseline: 2.7268x; 2.7268x over previous
//
#include <hip/hip_runtime.h>
#include <hip/hip_bf16.h>

// GNODE fully fused: y' = relu(y@W1+b1)@W2+b2, RK4(3/8) x10 steps (h=0.1),
// out = y@Wl+bl.  N=200000 rows, 128 ch, 64 out ch.
//
// Round 9: weights pinned in AGPRs (r7 was LDS-BW-bound: each MFMA needs a
// 1KB weight frag from LDS = 8-12 cy/CU vs 4.85 cy MFMA issue -> ~40% util
// ceiling; r8's 1024-thread variant crushed regs to 64 and spilled 7.7GB).
// - W1+W2 A-frags = 64 x bf16x8 = exactly 256 AGPRs, loaded once from
//   global and pinned via asm("" : "+a"(w)).  MFMA reads A from AGPR (AV
//   operand class on gfx950) -> ZERO LDS weight traffic in steady state.
// - 64-thread blocks (1 wave = 16 rows; n/16 = 12500 blocks exact), no
//   __syncthreads, LDS = 1KB biases only.
// - arch VGPR live set ~180 (y/U/V 96 + acc 32 + h 16 + misc) -> 1 wave/SIMD
//   (by design; 440 of 512 unified regs).  All overlap is same-wave ILP:
//   matrix window 1242 cy/feval vs ~900 cy VALU, no sched_barriers.
//
// State recurrences (template<MODE>):
//   M1: U<-k1   M2: V<-k2   M3: U<-U+3(V+k3), V<-U-V+k3   M4: y+=h/8(U+k4)
// Layout identity (mfma_f32_16x16x32_bf16, HW-verified m89):
//   D:      ch = 16*mb + 4*(lane>>4) + r,               batch = lane&15
//   B-frag: ch = 32*kb + 16*(j>>2) + 4*(lane>>4)+(j&3),  batch = lane&15
// => frag[e>>3][e&7] = state[e], e = 4*mb + r.  All lane-local.

typedef __attribute__((ext_vector_type(8))) short bf16x8;
typedef __attribute__((ext_vector_type(4))) float f32x4;

constexpr float HS = 0.1f;

__device__ __forceinline__ short bf16s(float f) {
    unsigned u = __builtin_bit_cast(unsigned, f);
    u += 0x7fffu + ((u >> 16) & 1u);          // RNE (finite data, no NaN)
    return (short)(u >> 16);
}

#define MFMA_BF16 __builtin_amdgcn_mfma_f32_16x16x32_bf16

template<int M>
__device__ __forceinline__ bf16x8 build_frag(const float (&y)[32], const float (&U)[32],
                                             const float (&V)[32], int kb) {
    bf16x8 f;
    #pragma unroll
    for (int j = 0; j < 8; ++j) {
        const int e = kb * 8 + j;
        float a;
        if (M == 1)      a = y[e];
        else if (M == 2) a = fmaf(HS * (1.f / 3.f), U[e], y[e]);
        else if (M == 3) a = fmaf(-HS * (1.f / 3.f), U[e], fmaf(HS, V[e], y[e]));
        else             a = fmaf(HS, V[e], y[e]);
        f[j] = bf16s(a);
    }
    return f;
}

// One f-eval; weights come straight from AGPR-resident frags.
template<int M>
__device__ __forceinline__ void feval(const bf16x8 (&w1)[32], const bf16x8 (&w2)[32],
                                      const float* __restrict__ sbf, int g,
                                      float (&y)[32], float (&U)[32], float (&V)[32])
{
    // acc = b1 (broadcast f32x4 LDS reads, no VALU)
    f32x4 acc[8];
    #pragma unroll
    for (int mb = 0; mb < 8; ++mb)
        acc[mb] = *(const f32x4*)&sbf[mb * 16 + g * 4];

    // ---- matmul1: 4 kb-groups x 8 MFMA, frag built JIT per kb
    #pragma unroll
    for (int kb = 0; kb < 4; ++kb) {
        bf16x8 f = build_frag<M>(y, U, V, kb);
        #pragma unroll
        for (int mb = 0; mb < 8; ++mb)
            acc[mb] = MFMA_BF16(w1[mb * 4 + kb], f, acc[mb], 0, 0, 0);
    }

    // ---- relu -> h frags
    bf16x8 h[4];
    #pragma unroll
    for (int mb = 0; mb < 8; ++mb)
        #pragma unroll
        for (int r = 0; r < 4; ++r)
            h[mb >> 1][(mb & 1) * 4 + r] = bf16s(fmaxf(acc[mb][r], 0.f));

    // ---- matmul2
    f32x4 acc2[8];
    #pragma unroll
    for (int mb = 0; mb < 8; ++mb)
        acc2[mb] = *(const f32x4*)&sbf[128 + mb * 16 + g * 4];
    #pragma unroll
    for (int kb = 0; kb < 4; ++kb)
        #pragma unroll
        for (int mb = 0; mb < 8; ++mb)
            acc2[mb] = MFMA_BF16(w2[mb * 4 + kb], h[kb], acc2[mb], 0, 0, 0);

    // ---- mode-fused writeback
    #pragma unroll
    for (int mb = 0; mb < 8; ++mb)
        #pragma unroll
        for (int r = 0; r < 4; ++r) {
            const int e = mb * 4 + r;
            const float k = acc2[mb][r];
            if (M == 1)      U[e] = k;
            else if (M == 2) V[e] = k;
            else if (M == 3) {
                const float u = U[e], v = V[e];
                U[e] = fmaf(3.f, v + k, u);
                V[e] = u - v + k;
            } else {
                y[e] = fmaf(HS * 0.125f, U[e] + k, y[e]);
            }
        }
}

__global__ __launch_bounds__(64) void gnode_kernel(
    const float* __restrict__ x, const uint4* __restrict__ wfr,
    const float* __restrict__ b1, const float* __restrict__ b2,
    const float* __restrict__ bl, float* __restrict__ out, int n)
{
    __shared__ float s_bf[256];      // 1KB: b1 [0..127], b2 [128..255]

    const int lane = threadIdx.x & 63;
    const int g    = lane >> 4;
    const int c16  = lane & 15;
    const int row  = blockIdx.x * 16 + c16;   // this lane's batch row
    const int rowc = row < n ? row : n - 1;

    // ---- biases into LDS (single wave: no barrier needed)
    #pragma unroll
    for (int i = 0; i < 4; ++i) {
        int idx = i * 64 + lane;
        s_bf[idx] = (idx < 128) ? b1[idx] : b2[idx - 128];
    }

    // ---- weights: load once, pin into AGPRs (exactly 256 AGPRs)
    bf16x8 w1[32], w2[32];
    #pragma unroll
    for (int f = 0; f < 32; ++f) {
        w1[f] = __builtin_bit_cast(bf16x8, wfr[f * 64 + lane]);
        asm volatile("" : "+a"(w1[f]));
    }
    #pragma unroll
    for (int f = 0; f < 32; ++f) {
        w2[f] = __builtin_bit_cast(bf16x8, wfr[(32 + f) * 64 + lane]);
        asm volatile("" : "+a"(w2[f]));
    }

    // Y^T state, fp32 master: elem e=4*mb+r <-> (ch = 16*mb+4*g+r, batch=row)
    float y[32];
    {
        const f32x4* x4 = (const f32x4*)x;
        #pragma unroll
        for (int cb = 0; cb < 8; ++cb) {
            f32x4 v = x4[(size_t)rowc * 32 + cb * 4 + g];
            y[cb * 4 + 0] = v[0]; y[cb * 4 + 1] = v[1];
            y[cb * 4 + 2] = v[2]; y[cb * 4 + 3] = v[3];
        }
    }

    float U[32], V[32];

    #pragma unroll 1
    for (int st = 0; st < 10; ++st) {
        feval<1>(w1, w2, s_bf, g, y, U, V);   // U <- k1
        feval<2>(w1, w2, s_bf, g, y, U, V);   // V <- k2
        feval<3>(w1, w2, s_bf, g, y, U, V);   // fold k3
        feval<4>(w1, w2, s_bf, g, y, U, V);   // y += h/8 (U + k4)
    }

    // ---- epilogue: out^T = Wl^T y^T + bl  (Wl frags straight from global)
    bf16x8 yf[4];
    #pragma unroll
    for (int e = 0; e < 32; ++e) yf[e >> 3][e & 7] = bf16s(y[e]);
    f32x4 ao[4];
    {
        const f32x4* bl4 = (const f32x4*)bl;
        #pragma unroll
        for (int mb = 0; mb < 4; ++mb) ao[mb] = bl4[mb * 4 + g];   // bl[16mb+4g+r]
    }
    #pragma unroll
    for (int f = 0; f < 16; ++f) {
        bf16x8 w = __builtin_bit_cast(bf16x8, wfr[(64 + f) * 64 + lane]);
        ao[f >> 2] = MFMA_BF16(w, yf[f & 3], ao[f >> 2], 0, 0, 0);
    }
    if (row < n) {
        f32x4* out4 = (f32x4*)out;
        #pragma unroll
        for (int mb = 0; mb < 4; ++mb)
            out4[(size_t)row * 16 + mb * 4 + g] = ao[mb];          // out[row][16mb+4g+r]
    }
}

// ---- prep: A-frag-linear bf16 weights into d_ws ----
// A-frag (16x32): lane l, elem j:  row = l&15 (+16*mb),
//                                  k   = 32*kb + 16*(j>>2) + 4*(l>>4) + (j&3)
// wfr[f*64+lane] : f 0..31 = W1 (mb=f>>2,kb=f&3), 32..63 = W2, 64..79 = Wl.
__global__ void prep_kernel(const float* __restrict__ W1, const float* __restrict__ W2,
                            const float* __restrict__ Wl, uint4* __restrict__ wfr)
{
    int t = blockIdx.x * 256 + threadIdx.x;
    if (t >= 80 * 64) return;
    int f = t >> 6, lane = t & 63;
    int gq = lane >> 4, c = lane & 15;
    const float* W; int mb, kv, cols;
    if (f < 32)      { W = W1; mb = f >> 2;        kv = f & 3;        cols = 128; }
    else if (f < 64) { W = W2; mb = (f - 32) >> 2; kv = (f - 32) & 3; cols = 128; }
    else             { W = Wl; mb = (f - 64) >> 2; kv = (f - 64) & 3; cols = 64;  }
    int col = mb * 16 + c;               // output-channel (A row)
    unsigned short v[8];
    #pragma unroll
    for (int j = 0; j < 8; ++j) {
        int k = kv * 32 + (j >> 2) * 16 + gq * 4 + (j & 3);
        unsigned u = __builtin_bit_cast(unsigned, W[k * cols + col]);
        u += 0x7fffu + ((u >> 16) & 1u);
        v[j] = (unsigned short)(u >> 16);
    }
    uint4 o;
    o.x = (unsigned)v[0] | ((unsigned)v[1] << 16);
    o.y = (unsigned)v[2] | ((unsigned)v[3] << 16);
    o.z = (unsigned)v[4] | ((unsigned)v[5] << 16);
    o.w = (unsigned)v[6] | ((unsigned)v[7] << 16);
    wfr[t] = o;
}

extern "C" void kernel_launch(void* const* d_in, const int* in_sizes, int n_in,
                              void* d_out, int out_size, void* d_ws, size_t ws_size,
                              hipStream_t stream)
{
    const float* x  = (const float*)d_in[0];
    const float* W1 = (const float*)d_in[1];
    const float* b1 = (const float*)d_in[2];
    const float* W2 = (const float*)d_in[3];
    const float* b2 = (const float*)d_in[4];
    const float* Wl = (const float*)d_in[5];
    const float* bl = (const float*)d_in[6];

    const int n = in_sizes[0] / 128;

    uint4* wfr = (uint4*)d_ws;                       // 80*64*16 = 81920 B

    prep_kernel<<<20, 256, 0, stream>>>(W1, W2, Wl, wfr);

    const int nb = (n + 15) / 16;            // 16 rows per block (1 wave)
    gnode_kernel<<<nb, 64, 0, stream>>>(x, wfr, b1, b2, bl, (float*)d_out, n);
}